// Round 2
// baseline (3102.718 us; speedup 1.0000x reference)
//
#include <hip/hip_runtime.h>
#include <stdint.h>

// ---------------------------------------------------------------------------
// ThermalLatticeSampler2D: checkerboard Metropolis + parallel tempering,
// bit-exact replication of jax.random (threefry2x32, partitionable mode).
//
// Round 2 fix: partitionable-mode random_bits for 32-bit draws is
// (bits1 ^ bits2), not bits1 alone (jax._src.prng).
//
// State: spins as float +-1 stored directly in d_out[0 : 32*16*256*256].
// Final energies written to d_out tail (512 floats).
// ---------------------------------------------------------------------------

#define BB 32
#define CC 16
#define LLAT 256
#define PLANE (LLAT * LLAT)          // 65536
#define NSITE (BB * CC * PLANE)      // 33554432
#define NPAIR ((BB - 1) * CC)        // 496

// Threefry-2x32, 20 rounds (matches jax._src.prng.threefry2x32 exactly).
__host__ __device__ __forceinline__ void tf2x32(uint32_t k0, uint32_t k1,
                                                uint32_t c0, uint32_t c1,
                                                uint32_t& o0, uint32_t& o1) {
  uint32_t ks2 = k0 ^ k1 ^ 0x1BD11BDAu;
  uint32_t x0 = c0 + k0;
  uint32_t x1 = c1 + k1;
#define TF_ROT(r) { x0 += x1; x1 = (x1 << (r)) | (x1 >> (32 - (r))); x1 ^= x0; }
  TF_ROT(13) TF_ROT(15) TF_ROT(26) TF_ROT(6)
  x0 += k1;  x1 += ks2 + 1u;
  TF_ROT(17) TF_ROT(29) TF_ROT(16) TF_ROT(24)
  x0 += ks2; x1 += k0 + 2u;
  TF_ROT(13) TF_ROT(15) TF_ROT(26) TF_ROT(6)
  x0 += k0;  x1 += k1 + 3u;
  TF_ROT(17) TF_ROT(29) TF_ROT(16) TF_ROT(24)
  x0 += k1;  x1 += ks2 + 4u;
  TF_ROT(13) TF_ROT(15) TF_ROT(26) TF_ROT(6)
  x0 += ks2; x1 += k0 + 5u;
#undef TF_ROT
  o0 = x0; o1 = x1;
}

// jax.random.uniform bit trick: [1,2) mantissa fill, minus 1.
__device__ __forceinline__ float u01(uint32_t bits) {
  return __uint_as_float((bits >> 9) | 0x3f800000u) - 1.0f;
}

// ---- init: int32 {0,1} -> float {-1,+1} -----------------------------------
__global__ __launch_bounds__(256) void init_k(const int* __restrict__ spins,
                                              float* __restrict__ s) {
  int i = blockIdx.x * 256 + threadIdx.x;          // over NSITE/4
  int4 v = ((const int4*)spins)[i];
  float4 o;
  o.x = (float)(v.x * 2 - 1);
  o.y = (float)(v.y * 2 - 1);
  o.z = (float)(v.z * 2 - 1);
  o.w = (float)(v.w * 2 - 1);
  ((float4*)s)[i] = o;
}

// ---- precompute Metropolis thresholds exp(-dE/T) (double exp -> f32) ------
__global__ void prep_k(const float* __restrict__ T,
                       float* __restrict__ thr4, float* __restrict__ thr8) {
  int b = threadIdx.x;
  if (b < BB) {
    float t = T[b];
    // reference: jnp.exp(-dE / T): fp32 division then fp32 exp.
    float x4 = (-4.0f) / t;
    float x8 = (-8.0f) / t;
    thr4[b] = (float)exp((double)x4);
    thr8[b] = (float)exp((double)x8);
  }
}

// ---- one checkerboard half-sweep ------------------------------------------
// Thread -> one site of the active color: tid = (((b*16+c)*256)+y)*128 + k,
// x = 2k + ((y+color)&1).  Random bits (partitionable mode, 32-bit draw):
// bits = o0 ^ o1 of threefry(key, (0, linear_site_index)).
__global__ __launch_bounds__(256) void half_sweep_k(float* __restrict__ s,
    const float* __restrict__ thr4, const float* __restrict__ thr8,
    uint32_t k0, uint32_t k1, int color, int t, const int* __restrict__ nsw) {
  if (t >= *nsw) return;
  int tid = blockIdx.x * 256 + threadIdx.x;
  int k  = tid & 127;
  int y  = (tid >> 7) & 255;
  int bc = tid >> 15;                  // b*16 + c
  int b  = bc >> 4;
  int x  = 2 * k + ((y + color) & 1);
  int plane = bc * PLANE;
  int row   = plane + (y << 8);

  float sv = s[row + x];
  float lf = s[row + ((x + 255) & 255)];
  float rt = s[row + ((x + 1) & 255)];
  float up = s[plane + (((y + 255) & 255) << 8) + x];
  float dn = s[plane + (((y + 1) & 255) << 8) + x];
  float prod = sv * (lf + rt + up + dn);   // in {-4,-2,0,2,4}; dE = 2*prod

  bool acc;
  if (prod <= 0.0f) {
    acc = true;                            // exp(-dE/T) >= 1 > u always
  } else {
    uint32_t idx = (uint32_t)(row + x);    // full linear site index
    uint32_t h0, h1;
    tf2x32(k0, k1, 0u, idx, h0, h1);
    float u = u01(h0 ^ h1);                // partitionable: xor both words
    float th = (prod == 2.0f) ? thr4[b] : thr8[b];
    acc = u < th;
  }
  if (acc) s[row + x] = -sv;
}

// ---- energy per (b,c) plane: E = -sum s*(right+down), exact integer -------
__global__ __launch_bounds__(256) void energy_k(const float* __restrict__ s,
                                                float* __restrict__ Edst) {
  int bc = blockIdx.x;
  const float* p = s + bc * PLANE;
  int tx = threadIdx.x;
  int acc = 0;
  for (int y = 0; y < 256; ++y) {
    int x = tx;
    float sv = p[(y << 8) + x];
    float rr = p[(y << 8) + ((x + 1) & 255)];
    float dd = p[(((y + 1) & 255) << 8) + x];
    acc += (int)sv * ((int)rr + (int)dd);
  }
  int lane = threadIdx.x & 63;
  int wid  = threadIdx.x >> 6;
  for (int off = 32; off > 0; off >>= 1) acc += __shfl_down(acc, off, 64);
  __shared__ int red[4];
  if (lane == 0) red[wid] = acc;
  __syncthreads();
  if (threadIdx.x == 0) {
    int tot = red[0] + red[1] + red[2] + red[3];
    Edst[bc] = -(float)tot;
  }
}

// ---- PT swap decision: acc = (u < exp(d)) & pair_mask ---------------------
__global__ void pt_decide_k(const float* __restrict__ E,
                            const float* __restrict__ T,
                            uint32_t k0, uint32_t k1, int pair_parity,
                            int* __restrict__ accf, int t,
                            const int* __restrict__ nsw) {
  if (t >= *nsw) return;
  int tid = threadIdx.x;
  if (tid >= NPAIR) return;
  int b = tid >> 4;            // 0..30
  int c = tid & 15;
  float beta_b  = 1.0f / T[b];
  float beta_b1 = 1.0f / T[b + 1];
  float d = (beta_b - beta_b1) * (E[b * CC + c] - E[(b + 1) * CC + c]);
  uint32_t h0, h1;
  tf2x32(k0, k1, 0u, (uint32_t)tid, h0, h1);   // uniform over (31,16), idx=b*16+c
  float u = u01(h0 ^ h1);                      // partitionable: xor both words
  float th = (float)exp((double)d);
  accf[tid] = (u < th) && ((b & 1) == pair_parity);
}

// ---- apply accepted swaps: exchange planes (b,c) <-> (b+1,c) --------------
__global__ __launch_bounds__(256) void pt_swap_k(float* __restrict__ s,
                                                 const int* __restrict__ accf,
                                                 int t, const int* __restrict__ nsw) {
  if (t >= *nsw) return;
  int pc = blockIdx.x;                 // 0..495 = b*16+c
  if (!accf[pc]) return;
  int b = pc >> 4, c = pc & 15;
  float* p0 = s + (b * CC + c) * PLANE;
  float* p1 = p0 + CC * PLANE;         // (b+1, c)
  for (int j = threadIdx.x; j < PLANE; j += 256) {
    float a0 = p0[j];
    float a1 = p1[j];
    p0[j] = a1;
    p1[j] = a0;
  }
}

extern "C" void kernel_launch(void* const* d_in, const int* in_sizes, int n_in,
                              void* d_out, int out_size, void* d_ws, size_t ws_size,
                              hipStream_t stream) {
  (void)in_sizes; (void)n_in; (void)out_size; (void)ws_size;
  const float* T    = (const float*)d_in[0];
  const int*  spins = (const int*)d_in[1];
  const int*  nsw   = (const int*)d_in[2];

  float* s    = (float*)d_out;          // 33,554,432 floats: spin state +-1
  float* Eout = s + NSITE;              // 512 floats: final energies

  float* Eplane = (float*)d_ws;         // 512
  float* thr4   = Eplane + BB * CC;     // 32
  float* thr8   = thr4 + BB;            // 32
  int*   accf   = (int*)(thr8 + BB);    // 496

  init_k<<<NSITE / 1024, 256, 0, stream>>>(spins, s);
  prep_k<<<1, 64, 0, stream>>>(T, thr4, thr8);

  // Key schedule on host (pure integer math, deterministic per t).
  for (int t = 0; t < 16; ++t) {
    uint32_t kb0, kb1;
    tf2x32(0u, 42u, 0u, (uint32_t)t, kb0, kb1);      // fold_in(key(42), t)
    uint32_t k1a, k1b, k2a, k2b, k3a, k3b;
    tf2x32(kb0, kb1, 0u, 0u, k1a, k1b);              // split -> subkey 0
    tf2x32(kb0, kb1, 0u, 1u, k2a, k2b);              // subkey 1
    tf2x32(kb0, kb1, 0u, 2u, k3a, k3b);              // subkey 2

    half_sweep_k<<<65536, 256, 0, stream>>>(s, thr4, thr8, k1a, k1b, 0, t, nsw);
    half_sweep_k<<<65536, 256, 0, stream>>>(s, thr4, thr8, k2a, k2b, 1, t, nsw);

    if (t % 4 == 3) {
      energy_k<<<BB * CC, 256, 0, stream>>>(s, Eplane);
      pt_decide_k<<<1, 512, 0, stream>>>(Eplane, T, k3a, k3b, (t / 4) % 2,
                                         accf, t, nsw);
      pt_swap_k<<<NPAIR, 256, 0, stream>>>(s, accf, t, nsw);
    }
  }

  energy_k<<<BB * CC, 256, 0, stream>>>(s, Eout);
}

// Round 3
// 1563.301 us; speedup vs baseline: 1.9847x; 1.9847x over previous
//
#include <hip/hip_runtime.h>
#include <stdint.h>

// ---------------------------------------------------------------------------
// ThermalLatticeSampler2D — round 3: int8 double-buffered state, fused
// color0+color1 sweep via LDS row strips, staged in-place fp32 expansion.
//
// Bit-exact jax.random (threefry2x32, partitionable mode) — validated R2.
// State buffers: buf0 = d_out bytes [0, N), buf1 = [N, 2N), N = 33554432.
// After 16 sweeps state is in buf0; energies -> d_out tail; then staged
// int8->fp32 expansion fills d_out[0, N) floats.
// ---------------------------------------------------------------------------

#define BB 32
#define CC 16
#define PLANE 65536                    // 256*256 bytes per (b,c) plane
#define NSITE (BB * CC * PLANE)        // 33554432
#define NPAIR ((BB - 1) * CC)          // 496
#define HSTRIP 32                      // rows stored per block
#define ROWS_LD (HSTRIP + 4)           // 36 rows loaded (halo 2 each side)

// Threefry-2x32, 20 rounds (matches jax._src.prng.threefry2x32 exactly).
__host__ __device__ __forceinline__ void tf2x32(uint32_t k0, uint32_t k1,
                                                uint32_t c0, uint32_t c1,
                                                uint32_t& o0, uint32_t& o1) {
  uint32_t ks2 = k0 ^ k1 ^ 0x1BD11BDAu;
  uint32_t x0 = c0 + k0;
  uint32_t x1 = c1 + k1;
#define TF_ROT(r) { x0 += x1; x1 = (x1 << (r)) | (x1 >> (32 - (r))); x1 ^= x0; }
  TF_ROT(13) TF_ROT(15) TF_ROT(26) TF_ROT(6)
  x0 += k1;  x1 += ks2 + 1u;
  TF_ROT(17) TF_ROT(29) TF_ROT(16) TF_ROT(24)
  x0 += ks2; x1 += k0 + 2u;
  TF_ROT(13) TF_ROT(15) TF_ROT(26) TF_ROT(6)
  x0 += k0;  x1 += k1 + 3u;
  TF_ROT(17) TF_ROT(29) TF_ROT(16) TF_ROT(24)
  x0 += k1;  x1 += ks2 + 4u;
  TF_ROT(13) TF_ROT(15) TF_ROT(26) TF_ROT(6)
  x0 += ks2; x1 += k0 + 5u;
#undef TF_ROT
  o0 = x0; o1 = x1;
}

__device__ __forceinline__ float u01(uint32_t bits) {
  return __uint_as_float((bits >> 9) | 0x3f800000u) - 1.0f;
}

// ---- init: int32 {0,1} -> int8 {-1,+1} into buf0 --------------------------
__global__ __launch_bounds__(256) void init8_k(const int* __restrict__ spins,
                                               int8_t* __restrict__ s) {
  int i = blockIdx.x * 256 + threadIdx.x;          // over NSITE/4
  int4 v = ((const int4*)spins)[i];
  uchar4 o;
  o.x = (uint8_t)(int8_t)(2 * v.x - 1);
  o.y = (uint8_t)(int8_t)(2 * v.y - 1);
  o.z = (uint8_t)(int8_t)(2 * v.z - 1);
  o.w = (uint8_t)(int8_t)(2 * v.w - 1);
  ((uchar4*)s)[i] = o;
}

// ---- precompute Metropolis thresholds exp(-dE/T) --------------------------
__global__ void prep_k(const float* __restrict__ T,
                       float* __restrict__ thr4, float* __restrict__ thr8) {
  int b = threadIdx.x;
  if (b < BB) {
    float t = T[b];
    thr4[b] = (float)exp((double)((-4.0f) / t));
    thr8[b] = (float)exp((double)((-8.0f) / t));
  }
}

// ---- fused sweep: color 0 then color 1, one strip of 32 rows per block ----
// Reads src (state after previous sweep), writes dst rows [y0, y0+32).
// Color-0 computed for rows [y0-1, y0+32] (halo rows redundant, identical
// across blocks since deterministic), color-1 for interior [y0, y0+32).
__global__ __launch_bounds__(256) void sweep_k(
    const int8_t* __restrict__ src, int8_t* __restrict__ dst,
    const float* __restrict__ thr4, const float* __restrict__ thr8,
    uint32_t kA0, uint32_t kA1, uint32_t kB0, uint32_t kB1,
    int t, const int* __restrict__ nsw) {
  __shared__ __align__(16) int8_t tile[ROWS_LD * 256];

  int bc    = blockIdx.x >> 3;            // plane index b*16+c
  int strip = blockIdx.x & 7;
  int y0    = strip * HSTRIP;
  int b     = bc >> 4;
  uint32_t bcbase = (uint32_t)bc << 16;
  const int8_t* sp = src + ((size_t)bc << 16);
  int8_t*       dp = dst + ((size_t)bc << 16);
  int tid = threadIdx.x;
  bool active = (t < *nsw);
  float t4 = thr4[b], t8 = thr8[b];

  // load 36 rows (576 uint4)
  for (int it = 0; it < 3; ++it) {
    int i = it * 256 + tid;
    if (i < ROWS_LD * 16) {
      int gy = (y0 - 2 + (i >> 4)) & 255;
      ((uint4*)tile)[i] = *(const uint4*)(sp + (gy << 8) + ((i & 15) << 4));
    }
  }
  __syncthreads();

  if (active) {
    int tq = tid >> 7;              // 0/1: which of 2 rows this iteration
    int k  = tid & 127;             // color-site index within row

    // ---- color 0: rows j in [1, 35) = global rows [y0-1, y0+32] ----------
    for (int it = 0; it < 17; ++it) {
      int j  = 1 + it * 2 + tq;
      int gy = (y0 - 2 + j) & 255;
      int x  = (k << 1) | (gy & 1);                 // (gy+x)%2 == 0
      int8_t sv = tile[j * 256 + x];
      int nsum = (int)tile[j * 256 + ((x + 1) & 255)]
               + (int)tile[j * 256 + ((x + 255) & 255)]
               + (int)tile[(j - 1) * 256 + x]
               + (int)tile[(j + 1) * 256 + x];
      int prod = (int)sv * nsum;                    // dE = 2*prod
      bool acc = true;
      if (prod > 0) {
        uint32_t h0, h1;
        tf2x32(kA0, kA1, 0u, bcbase + ((uint32_t)gy << 8) + (uint32_t)x, h0, h1);
        float u = u01(h0 ^ h1);
        acc = u < (prod == 2 ? t4 : t8);
      }
      if (acc) tile[j * 256 + x] = (int8_t)(-sv);
    }
    __syncthreads();

    // ---- color 1: rows j in [2, 34) = global rows [y0, y0+32) ------------
    for (int it = 0; it < 16; ++it) {
      int j  = 2 + it * 2 + tq;
      int gy = (y0 - 2 + j) & 255;
      int x  = (k << 1) | ((gy + 1) & 1);           // (gy+x)%2 == 1
      int8_t sv = tile[j * 256 + x];
      int nsum = (int)tile[j * 256 + ((x + 1) & 255)]
               + (int)tile[j * 256 + ((x + 255) & 255)]
               + (int)tile[(j - 1) * 256 + x]
               + (int)tile[(j + 1) * 256 + x];
      int prod = (int)sv * nsum;
      bool acc = true;
      if (prod > 0) {
        uint32_t h0, h1;
        tf2x32(kB0, kB1, 0u, bcbase + ((uint32_t)gy << 8) + (uint32_t)x, h0, h1);
        float u = u01(h0 ^ h1);
        acc = u < (prod == 2 ? t4 : t8);
      }
      if (acc) tile[j * 256 + x] = (int8_t)(-sv);
    }
  }
  __syncthreads();

  // store interior rows j in [2, 34) -> dst rows [y0, y0+32)  (512 uint4)
  for (int it = 0; it < 2; ++it) {
    int i = it * 256 + tid;
    int gy = y0 + (i >> 4);
    *(uint4*)(dp + (gy << 8) + ((i & 15) << 4)) = ((uint4*)tile)[32 + i];
  }
}

// ---- energy per plane from int8 state (exact integer, popcount trick) ----
__global__ __launch_bounds__(256) void energy8_k(const int8_t* __restrict__ s,
                                                 float* __restrict__ Edst) {
  int bc = blockIdx.x;
  const uint8_t* p = (const uint8_t*)(s + ((size_t)bc << 16));
  int tid = threadIdx.x;
  int xg = tid & 63;                 // 4-column group
  int acc = 0;                       // sum of s*(right+down)
  for (int i = 0; i < 64; ++i) {
    int y  = (tid >> 6) + i * 4;
    int y1 = (y + 1) & 255;
    uint32_t cur = *(const uint32_t*)(p + (y << 8) + (xg << 2));
    uint32_t nxt = *(const uint32_t*)(p + (y << 8) + (((xg + 1) & 63) << 2));
    uint32_t dwn = *(const uint32_t*)(p + (y1 << 8) + (xg << 2));
    uint32_t rsh = (cur >> 8) | (nxt << 24);
    // bytes are 0x01/0xFF: equal -> product +1, diff -> -1 (xor bit1 set)
    int d1 = __builtin_popcount((cur ^ rsh) & 0x02020202u);
    int d2 = __builtin_popcount((cur ^ dwn) & 0x02020202u);
    acc += 8 - 2 * (d1 + d2);
  }
  int lane = tid & 63, wid = tid >> 6;
  for (int off = 32; off > 0; off >>= 1) acc += __shfl_down(acc, off, 64);
  __shared__ int red[4];
  if (lane == 0) red[wid] = acc;
  __syncthreads();
  if (tid == 0) Edst[bc] = -(float)(red[0] + red[1] + red[2] + red[3]);
}

// ---- PT swap decision ------------------------------------------------------
__global__ void pt_decide_k(const float* __restrict__ E,
                            const float* __restrict__ T,
                            uint32_t k0, uint32_t k1, int pair_parity,
                            int* __restrict__ accf, int t,
                            const int* __restrict__ nsw) {
  int tid = threadIdx.x;
  if (tid >= NPAIR) return;
  if (t >= *nsw) { accf[tid] = 0; return; }
  int b = tid >> 4;
  float beta_b  = 1.0f / T[b];
  float beta_b1 = 1.0f / T[b + 1];
  float d = (beta_b - beta_b1) * (E[tid] - E[tid + CC]);
  uint32_t h0, h1;
  tf2x32(k0, k1, 0u, (uint32_t)tid, h0, h1);
  float u = u01(h0 ^ h1);
  float th = (float)exp((double)d);
  accf[tid] = (u < th) && ((b & 1) == pair_parity);
}

// ---- apply accepted swaps: exchange 64KB planes ---------------------------
__global__ __launch_bounds__(256) void pt_swap8_k(int8_t* __restrict__ s,
                                                  const int* __restrict__ accf) {
  int pc = blockIdx.x;
  if (!accf[pc]) return;
  uint4* p0 = (uint4*)(s + ((size_t)pc << 16));
  uint4* p1 = p0 + (CC * PLANE / 16);            // plane (b+1, c)
  for (int j = threadIdx.x; j < PLANE / 16; j += 256) {
    uint4 a0 = p0[j], a1 = p1[j];
    p0[j] = a1; p1[j] = a0;
  }
}

// ---- staged in-place int8 -> fp32 expansion -------------------------------
// Expands elements [lo, lo+cnt): reads bytes [lo, lo+cnt), writes floats
// [lo, lo+cnt) = bytes [4lo, 4(lo+cnt)). Disjoint when cnt <= 3*lo.
__global__ __launch_bounds__(256) void expand_k(const int8_t* __restrict__ st,
                                                float* __restrict__ out,
                                                int lo, int cnt4) {
  int i = blockIdx.x * 256 + threadIdx.x;        // over cnt/4
  if (i >= cnt4) return;
  uint32_t v = *(const uint32_t*)(st + lo + 4 * i);
  float4 o;
  o.x = (float)(int8_t)(v);
  o.y = (float)(int8_t)(v >> 8);
  o.z = (float)(int8_t)(v >> 16);
  o.w = (float)(int8_t)(v >> 24);
  ((float4*)out)[(lo >> 2) + i] = o;
}

// single block finishes elements [0, 8192) with an internal barrier
__global__ __launch_bounds__(256) void expand_head_k(const int8_t* __restrict__ st,
                                                     float* __restrict__ out) {
  uint32_t r[8];
  int t = threadIdx.x;
  for (int u = 0; u < 8; ++u) r[u] = *(const uint32_t*)(st + t * 32 + 4 * u);
  __syncthreads();
  for (int u = 0; u < 8; ++u) {
    uint32_t v = r[u];
    float4 o;
    o.x = (float)(int8_t)(v);
    o.y = (float)(int8_t)(v >> 8);
    o.z = (float)(int8_t)(v >> 16);
    o.w = (float)(int8_t)(v >> 24);
    ((float4*)out)[t * 8 + u] = o;
  }
}

extern "C" void kernel_launch(void* const* d_in, const int* in_sizes, int n_in,
                              void* d_out, int out_size, void* d_ws, size_t ws_size,
                              hipStream_t stream) {
  (void)in_sizes; (void)n_in; (void)out_size; (void)ws_size;
  const float* T    = (const float*)d_in[0];
  const int*  spins = (const int*)d_in[1];
  const int*  nsw   = (const int*)d_in[2];

  int8_t* buf0 = (int8_t*)d_out;                 // bytes [0, N)
  int8_t* buf1 = buf0 + NSITE;                   // bytes [N, 2N)
  float*  outf = (float*)d_out;
  float*  Eout = outf + NSITE;                   // 512 floats after spin region

  float* Eplane = (float*)d_ws;                  // 512
  float* thr4   = Eplane + BB * CC;              // 32
  float* thr8   = thr4 + BB;                     // 32
  int*   accf   = (int*)(thr8 + BB);             // 496

  init8_k<<<NSITE / 1024, 256, 0, stream>>>(spins, buf0);
  prep_k<<<1, 64, 0, stream>>>(T, thr4, thr8);

  for (int t = 0; t < 16; ++t) {
    uint32_t kb0, kb1;
    tf2x32(0u, 42u, 0u, (uint32_t)t, kb0, kb1);  // fold_in(key(42), t)
    uint32_t k1a, k1b, k2a, k2b, k3a, k3b;
    tf2x32(kb0, kb1, 0u, 0u, k1a, k1b);
    tf2x32(kb0, kb1, 0u, 1u, k2a, k2b);
    tf2x32(kb0, kb1, 0u, 2u, k3a, k3b);

    int8_t* src = (t & 1) ? buf1 : buf0;
    int8_t* dst = (t & 1) ? buf0 : buf1;
    sweep_k<<<BB * CC * 8, 256, 0, stream>>>(src, dst, thr4, thr8,
                                             k1a, k1b, k2a, k2b, t, nsw);
    if ((t & 3) == 3) {                          // dst == buf0 here (t odd)
      energy8_k<<<BB * CC, 256, 0, stream>>>(buf0, Eplane);
      pt_decide_k<<<1, 512, 0, stream>>>(Eplane, T, k3a, k3b, (t >> 2) & 1,
                                         accf, t, nsw);
      pt_swap8_k<<<NPAIR, 256, 0, stream>>>(buf0, accf);
    }
  }

  energy8_k<<<BB * CC, 256, 0, stream>>>(buf0, Eout);

  // staged in-place expansion (each stage reads [lo,4lo), writes [4lo,16lo))
  for (int lo = NSITE / 4; lo >= 8192; lo >>= 2) {
    int cnt4 = (lo * 3) / 4;                     // (4lo - lo)/4 elements of 4
    expand_k<<<(cnt4 + 255) / 256, 256, 0, stream>>>(buf0, outf, lo, cnt4);
  }
  expand_head_k<<<1, 256, 0, stream>>>(buf0, outf);
}